// Round 7
// baseline (211.788 us; speedup 1.0000x reference)
//
#include <hip/hip_runtime.h>

// YOLO loss. B=32, H=W=32, A=9, C=80, T=50, NET=512.
// Each wave owns 16 cells (5440 B/array, 16B-aligned). Stage: dense aligned
// dwordx4 stream loads -> scatter into pad-88 LDS tile (aligned b128 reads,
// bank-spread rows). Compute: 4 lanes/cell (R5's verified logic), box fields
// via broadcast LDS reads. No __syncthreads. Grid = 4608 blocks x 256.

constexpr int NT  = 50;
constexpr int PAD = 88;                 // 85 -> 88: rows stay 16B-aligned
typedef __attribute__((ext_vector_type(4))) float f4;

__global__ __launch_bounds__(256) void yolo_loss_kernel(
    const float* __restrict__ y_pred,     // (B,H,W,A,85) flat
    const float* __restrict__ y_true,     // (B,H,W,A,85)
    const float* __restrict__ true_boxes, // (B,50,4)
    const float* __restrict__ anchors,    // (9,2)
    float* __restrict__ out)              // (B,)
{
    __shared__ float sP[4][16 * PAD];     // 22528 B
    __shared__ float sT[4][16 * PAD];     // 22528 B
    __shared__ f4    s_box[4][NT];        // 3200 B
    __shared__ float s_area[4][NT];       // 800 B

    const int tid  = threadIdx.x;
    const int lane = tid & 63;
    const int wid  = tid >> 6;

    const int cellW = blockIdx.x * 64 + wid * 16;   // wave's first cell
    const int b     = (blockIdx.x * 64) / 9216;     // 144 blocks per image

    // ---- issue ALL global loads up front (aligned, dense, independent) ----
    const f4* gp4 = (const f4*)__builtin_assume_aligned(y_pred + (size_t)cellW * 85, 16);
    const f4* gt4 = (const f4*)__builtin_assume_aligned(y_true + (size_t)cellW * 85, 16);

    const f4 cp0 = gp4[lane];        const f4 ct0 = gt4[lane];
    const f4 cp1 = gp4[lane + 64];   const f4 ct1 = gt4[lane + 64];
    const f4 cp2 = gp4[lane + 128];  const f4 ct2 = gt4[lane + 128];
    const f4 cp3 = gp4[lane + 192];  const f4 ct3 = gt4[lane + 192];
    const f4 cp4 = gp4[lane + 256];  const f4 ct4 = gt4[lane + 256];
    f4 cp5 = {0.f,0.f,0.f,0.f}, ct5 = {0.f,0.f,0.f,0.f};
    if (lane < 20) { cp5 = gp4[lane + 320]; ct5 = gt4[lane + 320]; }

    f4 tb = {0.f,0.f,0.f,0.f};
    if (lane < NT) {
        const f4* tbp = (const f4*)__builtin_assume_aligned(true_boxes + (size_t)b * NT * 4, 16);
        tb = tbp[lane];
    }

    // ---- scatter: chunk c covers dwords q=4c..4c+3 of the 1360-dword span;
    //      g = q0/85 via magic (exact for q0<1360), field f0 = q0%85.
    //      Crossing a cell boundary bumps by PAD-85 = 3. ----
    float* wP = sP[wid];
    float* wT = sT[wid];
    auto scatter = [](float* base, f4 v, int c) {
        const int q0 = 4 * c;
        const int g  = (q0 * 49345) >> 22;
        const int f0 = q0 - 85 * g;
        float* d = base + g * PAD + f0;
        d[0] = v[0];
        d[1 + (f0 >= 84 ? 3 : 0)] = v[1];
        d[2 + (f0 >= 83 ? 3 : 0)] = v[2];
        d[3 + (f0 >= 82 ? 3 : 0)] = v[3];
    };
    scatter(wP, cp0, lane);        scatter(wT, ct0, lane);
    scatter(wP, cp1, lane + 64);   scatter(wT, ct1, lane + 64);
    scatter(wP, cp2, lane + 128);  scatter(wT, ct2, lane + 128);
    scatter(wP, cp3, lane + 192);  scatter(wT, ct3, lane + 192);
    scatter(wP, cp4, lane + 256);  scatter(wT, ct4, lane + 256);
    if (lane < 20) { scatter(wP, cp5, lane + 320); scatter(wT, ct5, lane + 320); }

    // ---- per-wave IoU table ----
    if (lane < NT) {
        const float tx = tb[0] * (1.0f / 32.0f);
        const float ty = tb[1] * (1.0f / 32.0f);
        const float tw = tb[2] * (1.0f / 512.0f);
        const float th = tb[3] * (1.0f / 512.0f);
        f4 e;
        e[0] = tx - tw * 0.5f;  e[1] = tx + tw * 0.5f;
        e[2] = ty - th * 0.5f;  e[3] = ty + th * 0.5f;
        s_box[wid][lane]  = e;
        s_area[wid][lane] = tw * th;
    }

    // wave-local fence: all ds_writes done before any ds_read; memory clobber
    // stops the compiler reordering LDS reads above this point.
    asm volatile("s_waitcnt lgkmcnt(0)" ::: "memory");

    // ---- compute: 4 lanes per cell ----
    const int s = lane & 3;
    const int g = lane >> 2;

    const int cell  = cellW + g;
    const int local = cell - b * 9216;
    const int a = local % 9;
    const int w = (local / 9) % 32;
    const int h = local / 288;

    const float* cP = wP + g * PAD;
    const float* cT = wT + g * PAD;

    // box fields: broadcast reads (4 lanes of a group hit the same address)
    const f4 pb  = *(const f4*)cP;
    const f4 tbx = *(const f4*)cT;
    const float p4v = cP[4], t4v = cT[4];

    // class slices: lane s owns fields 16j+4s+e (aligned b128 reads)
    const f4 pv0 = *(const f4*)(cP + 4 * s);
    const f4 pv1 = *(const f4*)(cP + 16 + 4 * s);
    const f4 pv2 = *(const f4*)(cP + 32 + 4 * s);
    const f4 pv3 = *(const f4*)(cP + 48 + 4 * s);
    const f4 pv4 = *(const f4*)(cP + 64 + 4 * s);
    const f4 tv0 = *(const f4*)(cT + 4 * s);
    const f4 tv1 = *(const f4*)(cT + 16 + 4 * s);
    const f4 tv2 = *(const f4*)(cT + 32 + 4 * s);
    const f4 tv3 = *(const f4*)(cT + 48 + 4 * s);
    const f4 tv4 = *(const f4*)(cT + 64 + 4 * s);
    f4 pt = {0.f,0.f,0.f,0.f}, ttl = {0.f,0.f,0.f,0.f};
    float p84 = 0.f, t84 = 0.f;
    if (s == 0) { pt  = *(const f4*)(cP + 80); ttl = *(const f4*)(cT + 80); }
    if (s == 1) { p84 = cP[84]; t84 = cT[84]; }

    const float aw = anchors[a * 2 + 0];
    const float ah = anchors[a * 2 + 1];

    // ---- geometry (group-uniform, redundant on 4 lanes) ----
    const float p0 = pb[0], p1 = pb[1], p2 = pb[2], p3 = pb[3], p4 = p4v;
    const float t0 = tbx[0], t1 = tbx[1], t2 = tbx[2], t3 = tbx[3], t4 = t4v;

    const float sig0  = 1.0f / (1.0f + __expf(-p0));
    const float sig1  = 1.0f / (1.0f + __expf(-p1));
    const float predx = (float)w + sig0;
    const float predy = (float)h + sig1;
    const float pconf = 1.0f / (1.0f + __expf(-p4));

    const float px = predx * (1.0f / 32.0f);
    const float py = predy * (1.0f / 32.0f);
    const float pw = __expf(p2) * aw * (1.0f / 512.0f);
    const float ph = __expf(p3) * ah * (1.0f / 512.0f);
    const float pminx = px - pw * 0.5f, pmaxx = px + pw * 0.5f;
    const float pminy = py - ph * 0.5f, pmaxy = py + ph * 0.5f;
    const float parea = pw * ph;

    // ---- IoU ignore flag (boxes 4i+s per lane) ----
    int ig = 0;
    #pragma unroll
    for (int i = 0; i < 13; ++i) {
        const int box = 4 * i + s;
        if (box < NT) {
            const f4 e = s_box[wid][box];
            float iw = fminf(pmaxx, e[1]) - fmaxf(pminx, e[0]);
            float ih = fminf(pmaxy, e[3]) - fmaxf(pminy, e[2]);
            iw = fmaxf(iw, 0.0f);
            ih = fmaxf(ih, 0.0f);
            const float inter = iw * ih;
            const float uni   = parea + s_area[wid][box] - inter;
            ig |= (2.0f * inter >= uni) ? 1 : 0;
        }
    }

    // ---- classes pass 1: argmax(true) carrying pred, and max(pred) ----
    float tmax = -1e30f, p_at = 0.0f, pmax = -1e30f;
    int   tidx = 1 << 20;
#define STEP1(PV, TV, J, E) {                                              \
        const bool cls = ((J) > 0) || (4 * s + (E) >= 5);                  \
        const float tcm = cls ? (TV)[(E)] : -1e30f;                        \
        const float pc  = (PV)[(E)];                                       \
        if (tcm > tmax) { tmax = tcm; p_at = pc; tidx = 16*(J)+4*s+(E); }  \
        pmax = fmaxf(pmax, cls ? pc : -1e30f); }
#define SLICE1(PV, TV, J) STEP1(PV,TV,J,0) STEP1(PV,TV,J,1) STEP1(PV,TV,J,2) STEP1(PV,TV,J,3)
    SLICE1(pv0, tv0, 0) SLICE1(pv1, tv1, 1) SLICE1(pv2, tv2, 2)
    SLICE1(pv3, tv3, 3) SLICE1(pv4, tv4, 4)
#define TAIL1(E) {                                                         \
        const float tcm = (s == 0) ? ttl[(E)] : -1e30f;                    \
        if (tcm > tmax) { tmax = tcm; p_at = pt[(E)]; tidx = 80 + (E); }   \
        pmax = fmaxf(pmax, (s == 0) ? pt[(E)] : -1e30f); }
    TAIL1(0) TAIL1(1) TAIL1(2) TAIL1(3)
    {
        const float tcm = (s == 1) ? t84 : -1e30f;
        if (tcm > tmax) { tmax = tcm; p_at = p84; tidx = 84; }
        pmax = fmaxf(pmax, (s == 1) ? p84 : -1e30f);
    }

    // combine across the 4 lanes of the group
    #pragma unroll
    for (int d = 1; d <= 2; d <<= 1) {
        const float ot = __shfl_xor(tmax, d);
        const float op = __shfl_xor(p_at, d);
        const int   oi = __shfl_xor(tidx, d);
        const bool upd = (ot > tmax) || (ot == tmax && oi < tidx);
        tmax = upd ? ot : tmax;
        p_at = upd ? op : p_at;
        tidx = upd ? oi : tidx;
        pmax = fmaxf(pmax, __shfl_xor(pmax, d));
        ig  |= __shfl_xor(ig, d);
    }

    // ---- classes pass 2: sum exp(pred - pmax), 4 accumulator streams ----
    f4 acc = {0.f, 0.f, 0.f, 0.f};
#define STEP2(PV, J, E) {                                                  \
        const bool cls = ((J) > 0) || (4 * s + (E) >= 5);                  \
        acc[(E)] += cls ? __expf((PV)[(E)] - pmax) : 0.0f; }
#define SLICE2(PV, J) STEP2(PV,J,0) STEP2(PV,J,1) STEP2(PV,J,2) STEP2(PV,J,3)
    SLICE2(pv0, 0) SLICE2(pv1, 1) SLICE2(pv2, 2) SLICE2(pv3, 3) SLICE2(pv4, 4)
    #pragma unroll
    for (int e = 0; e < 4; ++e)
        acc[e] += (s == 0) ? __expf(pt[e] - pmax) : 0.0f;
    acc[0] += (s == 1) ? __expf(p84 - pmax) : 0.0f;

    float sum = (acc[0] + acc[1]) + (acc[2] + acc[3]);
    sum += __shfl_xor(sum, 1);
    sum += __shfl_xor(sum, 2);
    const float ce = (pmax + __logf(sum)) - p_at;

    // ---- deltas ----
    const float om  = t4;
    const float ew  = __expf(t2) * aw * (1.0f / 512.0f);
    const float eh  = __expf(t3) * ah * (1.0f / 512.0f);
    const float whs = 2.0f - ew * eh;

    const float xyd0 = om * (predx - t0) * whs;
    const float xyd1 = om * (predy - t1) * whs;
    const float whd0 = om * (p2 - t2) * whs;
    const float whd1 = om * (p3 - t3) * whs;
    const float cd   = om * (pconf - t4) * 5.0f + (1.0f - om) * (ig ? 0.0f : pconf);

    float partial = xyd0 * xyd0 + xyd1 * xyd1 + whd0 * whd0 + whd1 * whd1 +
                    cd * cd + om * ce;

    // ---- wave-level sum of the 16 group leaders; one atomic per wave ----
    partial = (s == 0) ? partial : 0.0f;
    partial += __shfl_xor(partial, 4);
    partial += __shfl_xor(partial, 8);
    partial += __shfl_xor(partial, 16);
    partial += __shfl_xor(partial, 32);
    if (lane == 0)
        atomicAdd(&out[b], partial);
}

extern "C" void kernel_launch(void* const* d_in, const int* in_sizes, int n_in,
                              void* d_out, int out_size, void* d_ws, size_t ws_size,
                              hipStream_t stream) {
    // setup_inputs order: input_image (unused), y_pred, y_true, true_boxes, anchors
    const float* y_pred     = (const float*)d_in[1];
    const float* y_true     = (const float*)d_in[2];
    const float* true_boxes = (const float*)d_in[3];
    const float* anchors    = (const float*)d_in[4];
    float* out = (float*)d_out;

    hipMemsetAsync(d_out, 0, (size_t)out_size * sizeof(float), stream);

    dim3 grid(294912 / 64);   // 4608 blocks, 64 cells each (16 per wave)
    yolo_loss_kernel<<<grid, 256, 0, stream>>>(y_pred, y_true, true_boxes, anchors, out);
}

// Round 8
// 37.996 us; speedup vs baseline: 5.5740x; 5.5740x over previous
//
#include <hip/hip_runtime.h>

// YOLO loss. B=32, H=W=32, A=9, C=80, T=50, NET=512.
// Stage 1: R2's proven structure — 4 lanes cooperate per cell
// (component-interleaved loads: lane s reads floats idx = 4j+s).
// Block = 256 threads = 64 cells. Grid = 4608 blocks (144 per batch).
// Block partial -> plain store to d_ws[blockIdx.x]  (NO atomics: same-line
// atomicAdd serialization was the 3x limiter across R4-R6).
// Stage 2: 32 blocks x 1 wave sum 144 partials each -> out[b].

constexpr int NT = 50;

__global__ __launch_bounds__(256) void yolo_loss_kernel(
    const float* __restrict__ y_pred,     // (B,H,W,A,85) flat
    const float* __restrict__ y_true,     // (B,H,W,A,85)
    const float* __restrict__ true_boxes, // (B,50,4)
    const float* __restrict__ anchors,    // (9,2)
    float* __restrict__ ws)               // (4608,) block partials
{
    __shared__ float s_tminx[NT], s_tminy[NT], s_tmaxx[NT], s_tmaxy[NT], s_tarea[NT];
    __shared__ float s_anch[18];
    __shared__ float s_red[4];

    const int cell0 = blockIdx.x * 64;       // 64 cells per block, same batch b
    const int b     = cell0 / 9216;

    if (threadIdx.x < NT) {
        const float* tb = true_boxes + ((size_t)b * NT + threadIdx.x) * 4;
        float tx = tb[0] * (1.0f / 32.0f);
        float ty = tb[1] * (1.0f / 32.0f);
        float tw = tb[2] * (1.0f / 512.0f);
        float th = tb[3] * (1.0f / 512.0f);
        s_tminx[threadIdx.x] = tx - tw * 0.5f;
        s_tmaxx[threadIdx.x] = tx + tw * 0.5f;
        s_tminy[threadIdx.x] = ty - th * 0.5f;
        s_tmaxy[threadIdx.x] = ty + th * 0.5f;
        s_tarea[threadIdx.x] = tw * th;
    }
    if (threadIdx.x < 18) s_anch[threadIdx.x] = anchors[threadIdx.x];
    __syncthreads();

    const int s    = threadIdx.x & 3;        // slice within cell group
    const int g    = threadIdx.x >> 2;       // cell group within block: 0..63
    const int lane = threadIdx.x & 63;
    const int gb   = lane & ~3;              // group base lane in wave

    const int cell  = cell0 + g;
    const int local = cell - b * 9216;
    const int a = local % 9;
    const int w = (local / 9) % 32;
    const int h = local / 288;

    const size_t base = (size_t)cell * 85 + s;
    const float* P = y_pred + base;
    const float* T = y_true + base;

    // ---- coalesced interleaved loads: lane s owns floats idx = 4j+s ----
    float pv[21], tv[21];
    #pragma unroll
    for (int j = 0; j < 21; ++j) pv[j] = P[4 * j];
    #pragma unroll
    for (int j = 0; j < 21; ++j) tv[j] = T[4 * j];
    float p84 = 0.0f, t84 = 0.0f;
    if (s == 0) { p84 = P[84]; t84 = T[84]; }   // idx 84 (class 79), s=0 only

    // ---- gather box fields via shuffles (idx n lives on lane gb+n, v[0];
    //      idx 4 lives on lane gb+0, v[1]) ----
    const float p0 = __shfl(pv[0], gb + 0);
    const float p1 = __shfl(pv[0], gb + 1);
    const float p2 = __shfl(pv[0], gb + 2);
    const float p3 = __shfl(pv[0], gb + 3);
    const float p4 = __shfl(pv[1], gb + 0);
    const float t0 = __shfl(tv[0], gb + 0);
    const float t1 = __shfl(tv[0], gb + 1);
    const float t2 = __shfl(tv[0], gb + 2);
    const float t3 = __shfl(tv[0], gb + 3);
    const float t4 = __shfl(tv[1], gb + 0);

    const float aw = s_anch[a * 2 + 0];
    const float ah = s_anch[a * 2 + 1];

    // ---- geometry (computed redundantly on all 4 lanes) ----
    const float sig0  = 1.0f / (1.0f + __expf(-p0));
    const float sig1  = 1.0f / (1.0f + __expf(-p1));
    const float predx = (float)w + sig0;
    const float predy = (float)h + sig1;
    const float pconf = 1.0f / (1.0f + __expf(-p4));

    const float px = predx * (1.0f / 32.0f);
    const float py = predy * (1.0f / 32.0f);
    const float pw = __expf(p2) * aw * (1.0f / 512.0f);
    const float ph = __expf(p3) * ah * (1.0f / 512.0f);
    const float pminx = px - pw * 0.5f, pmaxx = px + pw * 0.5f;
    const float pminy = py - ph * 0.5f, pmaxy = py + ph * 0.5f;
    const float parea = pw * ph;

    // ---- IoU ignore flag, split 12-13 boxes per lane ----
    // best_iou >= 0.5  <=>  exists t: 2*inter >= union (union>0 always)
    int ig = 0;
    #pragma unroll
    for (int i = 0; i < 13; ++i) {
        const int box = i * 4 + s;
        if (box < NT) {
            float iw = fminf(pmaxx, s_tmaxx[box]) - fmaxf(pminx, s_tminx[box]);
            float ih = fminf(pmaxy, s_tmaxy[box]) - fmaxf(pminy, s_tminy[box]);
            iw = fmaxf(iw, 0.0f);
            ih = fmaxf(ih, 0.0f);
            float inter = iw * ih;
            float uni   = parea + s_tarea[box] - inter;
            ig |= (2.0f * inter >= uni) ? 1 : 0;
        }
    }
    ig |= __shfl_xor(ig, 1);
    ig |= __shfl_xor(ig, 2);

    // ---- classes: lane s owns classes at idx=4j+s (j>=1; j>=2 for s==0;
    //      plus idx84 for s==0). 20 classes per lane, 2 online streams. ----
    float tm[2] = { -1e30f, -1e30f }, pa[2] = { 0.0f, 0.0f };
    float mm[2] = { -1e30f, -1e30f }, ss[2] = { 0.0f, 0.0f };

    #pragma unroll
    for (int j = 1; j <= 21; ++j) {
        const int k = j & 1;
        float tc, pc;
        bool valid;
        if (j < 21) { valid = (j >= 2) || (s != 0); tc = tv[j]; pc = pv[j]; }
        else        { valid = (s == 0);             tc = t84;   pc = p84;   }
        const float tcm = valid ? tc : -1e30f;
        const float pcm = valid ? pc : -1e30f;
        const bool upd = tcm > tm[k];
        tm[k] = upd ? tcm : tm[k];
        pa[k] = upd ? pc  : pa[k];
        const float mn = fmaxf(mm[k], pcm);
        ss[k] = ss[k] * __expf(mm[k] - mn) + __expf(pcm - mn);
        mm[k] = mn;
    }
    // combine the 2 streams
    float tmax = tm[0], p_at = pa[0];
    {
        const bool upd = tm[1] > tmax;
        tmax = upd ? tm[1] : tmax;
        p_at = upd ? pa[1] : p_at;
    }
    float m  = fmaxf(mm[0], mm[1]);
    float sv = ss[0] * __expf(mm[0] - m) + ss[1] * __expf(mm[1] - m);
    // combine across the 4 lanes (butterfly)
    #pragma unroll
    for (int d = 1; d <= 2; d <<= 1) {
        const float om_ = __shfl_xor(m, d);
        const float os_ = __shfl_xor(sv, d);
        const float mn  = fmaxf(m, om_);
        sv = sv * __expf(m - mn) + os_ * __expf(om_ - mn);
        m  = mn;
        const float ot = __shfl_xor(tmax, d);
        const float op = __shfl_xor(p_at, d);
        const bool upd = ot > tmax;
        tmax = upd ? ot : tmax;
        p_at = upd ? op : p_at;
    }
    const float ce = (m + __logf(sv)) - p_at;

    // ---- deltas (lane s==0 emits the cell's partial) ----
    const float om  = t4;
    const float ew  = __expf(t2) * aw * (1.0f / 512.0f);
    const float eh  = __expf(t3) * ah * (1.0f / 512.0f);
    const float whs = 2.0f - ew * eh;

    const float xyd0 = om * (predx - t0) * whs;
    const float xyd1 = om * (predy - t1) * whs;
    const float whd0 = om * (p2 - t2) * whs;
    const float whd1 = om * (p3 - t3) * whs;
    const float cd   = om * (pconf - t4) * 5.0f + (1.0f - om) * (ig ? 0.0f : pconf);

    float partial = xyd0 * xyd0 + xyd1 * xyd1 + whd0 * whd0 + whd1 * whd1 +
                    cd * cd + om * ce;
    partial = (s == 0) ? partial : 0.0f;

    // ---- wave + block reduction, plain store (NO atomic) ----
    #pragma unroll
    for (int off = 32; off > 0; off >>= 1)
        partial += __shfl_down(partial, off);

    const int wid = threadIdx.x >> 6;
    if (lane == 0) s_red[wid] = partial;
    __syncthreads();
    if (threadIdx.x == 0)
        ws[blockIdx.x] = s_red[0] + s_red[1] + s_red[2] + s_red[3];
}

// Stage 2: one wave per batch sums its 144 block partials.
__global__ __launch_bounds__(64) void yolo_reduce_kernel(
    const float* __restrict__ ws,   // (4608,) = (32, 144)
    float* __restrict__ out)        // (B,)
{
    const int b    = blockIdx.x;
    const int lane = threadIdx.x;
    const float* p = ws + b * 144;

    float v = p[lane] + p[lane + 64] + ((lane < 16) ? p[lane + 128] : 0.0f);
    #pragma unroll
    for (int off = 32; off > 0; off >>= 1)
        v += __shfl_down(v, off);
    if (lane == 0) out[b] = v;
}

extern "C" void kernel_launch(void* const* d_in, const int* in_sizes, int n_in,
                              void* d_out, int out_size, void* d_ws, size_t ws_size,
                              hipStream_t stream) {
    // setup_inputs order: input_image (unused), y_pred, y_true, true_boxes, anchors
    const float* y_pred     = (const float*)d_in[1];
    const float* y_true     = (const float*)d_in[2];
    const float* true_boxes = (const float*)d_in[3];
    const float* anchors    = (const float*)d_in[4];
    float* out = (float*)d_out;
    float* ws  = (float*)d_ws;   // 4608 floats; fully written before read

    dim3 grid(294912 / 64);      // 4608 blocks, 64 cells each
    yolo_loss_kernel<<<grid, 256, 0, stream>>>(y_pred, y_true, true_boxes, anchors, ws);
    yolo_reduce_kernel<<<32, 64, 0, stream>>>(ws, out);
}